// Round 1
// baseline (626.093 us; speedup 1.0000x reference)
//
#include <hip/hip_runtime.h>
#include <math.h>

// Problem constants (from reference)
#define NN 50000
#define NE 800000
#define NFEAT 128
#define NHID 64
#define NCLASS 16

// ---------------- CSR build ----------------

__global__ __launch_bounds__(256) void hist_kernel(const int* __restrict__ row,
                                                   int* __restrict__ deg, int E) {
    int e = blockIdx.x * 256 + threadIdx.x;
    if (e < E) atomicAdd(&deg[row[e]], 1);
}

// One block of 1024 threads: exclusive scan of deg[0..n) -> row_ptr[0..n], cursor[0..n)
__global__ __launch_bounds__(1024) void scan_kernel(const int* __restrict__ deg,
                                                    int* __restrict__ row_ptr,
                                                    int* __restrict__ cursor, int n) {
    __shared__ int sums[1024];
    const int t = threadIdx.x;
    const int C = (n + 1023) / 1024;
    const int lo = t * C;
    const int hi = (lo + C < n) ? (lo + C) : n;
    int s = 0;
    for (int i = lo; i < hi; i++) s += deg[i];
    sums[t] = s;
    __syncthreads();
    // Hillis-Steele inclusive scan over 1024 partials
    for (int off = 1; off < 1024; off <<= 1) {
        int u = (t >= off) ? sums[t - off] : 0;
        __syncthreads();
        sums[t] += u;
        __syncthreads();
    }
    int prefix = (t == 0) ? 0 : sums[t - 1];  // exclusive prefix of this chunk
    for (int i = lo; i < hi; i++) {
        int d = deg[i];
        row_ptr[i] = prefix;
        cursor[i] = prefix;
        prefix += d;
    }
    if (t == 1023) row_ptr[n] = sums[1023];
}

__global__ __launch_bounds__(256) void scatter_kernel(const int* __restrict__ row,
                                                      const int* __restrict__ col,
                                                      const float* __restrict__ w,
                                                      int* __restrict__ cursor,
                                                      int* __restrict__ col_s,
                                                      float* __restrict__ w_s, int E) {
    int e = blockIdx.x * 256 + threadIdx.x;
    if (e < E) {
        int r = row[e];
        int pos = atomicAdd(&cursor[r], 1);
        col_s[pos] = col[e];
        w_s[pos] = w[e];
    }
}

// ---------------- Dense GEMM: out[M,NOUT] = in[M,K] @ W[K,NOUT] ----------------
// Block = 256 threads. GROUPS = 256/NOUT groups, each handles RPT consecutive rows.
// Rows per block = GROUPS*RPT (must divide M). W staged in LDS.
template <int K, int NOUT, int RPT>
__global__ __launch_bounds__(256) void gemm_kernel(const float* __restrict__ in,
                                                   const float* __restrict__ Wg,
                                                   float* __restrict__ out, int M) {
    __shared__ float Wl[K * NOUT];
    for (int i = threadIdx.x * 4; i < K * NOUT; i += 256 * 4) {
        *(float4*)&Wl[i] = *(const float4*)&Wg[i];
    }
    __syncthreads();

    constexpr int GROUPS = 256 / NOUT;
    constexpr int RPB = GROUPS * RPT;
    const int col = threadIdx.x % NOUT;
    const int grp = threadIdx.x / NOUT;
    const int r = blockIdx.x * RPB + grp * RPT;
    if (r >= M) return;

    float acc[RPT];
#pragma unroll
    for (int j = 0; j < RPT; j++) acc[j] = 0.f;

    const float* pr = in + (size_t)r * K;
#pragma unroll 2
    for (int k = 0; k < K; k += 4) {
        float w0 = Wl[(k + 0) * NOUT + col];
        float w1 = Wl[(k + 1) * NOUT + col];
        float w2 = Wl[(k + 2) * NOUT + col];
        float w3 = Wl[(k + 3) * NOUT + col];
#pragma unroll
        for (int j = 0; j < RPT; j++) {
            float4 xv = *(const float4*)(pr + j * K + k);
            acc[j] += xv.x * w0;
            acc[j] += xv.y * w1;
            acc[j] += xv.z * w2;
            acc[j] += xv.w * w3;
        }
    }
#pragma unroll
    for (int j = 0; j < RPT; j++) {
        out[(size_t)(r + j) * NOUT + col] = acc[j];
    }
}

// ---------------- SpMM: e_out[r,f] = sum_{e in row r} w_s[e]*tmp[col_s[e],f] + bias[f]
// Optionally writes relu to h_out. Block 256, 256/F rows per block, lane=feature.
template <int F, bool RELU>
__global__ __launch_bounds__(256) void spmm_kernel(const float* __restrict__ tmp,
                                                   const int* __restrict__ row_ptr,
                                                   const int* __restrict__ col_s,
                                                   const float* __restrict__ w_s,
                                                   const float* __restrict__ bias,
                                                   float* __restrict__ e_out,
                                                   float* __restrict__ h_out, int M) {
    constexpr int RPB = 256 / F;
    const int f = threadIdx.x % F;
    const int rl = threadIdx.x / F;
    const int r = blockIdx.x * RPB + rl;
    if (r >= M) return;

    const int start = row_ptr[r];
    const int end = row_ptr[r + 1];
    float acc = 0.f;
    int e = start;
    for (; e + 3 < end; e += 4) {
        int c0 = col_s[e + 0], c1 = col_s[e + 1], c2 = col_s[e + 2], c3 = col_s[e + 3];
        float w0 = w_s[e + 0], w1 = w_s[e + 1], w2 = w_s[e + 2], w3 = w_s[e + 3];
        acc += w0 * tmp[(size_t)c0 * F + f];
        acc += w1 * tmp[(size_t)c1 * F + f];
        acc += w2 * tmp[(size_t)c2 * F + f];
        acc += w3 * tmp[(size_t)c3 * F + f];
    }
    for (; e < end; e++) {
        acc += w_s[e] * tmp[(size_t)col_s[e] * F + f];
    }
    float v = acc + bias[f];
    e_out[(size_t)r * F + f] = v;
    if (RELU) h_out[(size_t)r * F + f] = fmaxf(v, 0.f);
}

// ---------------- log_softmax over 16 classes, one row per thread ----------------
__global__ __launch_bounds__(256) void logsoftmax_kernel(const float* __restrict__ e5,
                                                         float* __restrict__ out, int M) {
    int r = blockIdx.x * 256 + threadIdx.x;
    if (r >= M) return;
    float v[NCLASS];
    const float4* p = (const float4*)(e5 + (size_t)r * NCLASS);
#pragma unroll
    for (int i = 0; i < NCLASS / 4; i++) {
        float4 t = p[i];
        v[4 * i + 0] = t.x;
        v[4 * i + 1] = t.y;
        v[4 * i + 2] = t.z;
        v[4 * i + 3] = t.w;
    }
    float m = v[0];
#pragma unroll
    for (int i = 1; i < NCLASS; i++) m = fmaxf(m, v[i]);
    float s = 0.f;
#pragma unroll
    for (int i = 0; i < NCLASS; i++) s += expf(v[i] - m);
    float ls = logf(s);
    float4* q = (float4*)(out + (size_t)r * NCLASS);
#pragma unroll
    for (int i = 0; i < NCLASS / 4; i++) {
        float4 t;
        t.x = v[4 * i + 0] - m - ls;
        t.y = v[4 * i + 1] - m - ls;
        t.z = v[4 * i + 2] - m - ls;
        t.w = v[4 * i + 3] - m - ls;
        q[i] = t;
    }
}

// ---------------- launch ----------------

extern "C" void kernel_launch(void* const* d_in, const int* in_sizes, int n_in,
                              void* d_out, int out_size, void* d_ws, size_t ws_size,
                              hipStream_t stream) {
    const float* x = (const float*)d_in[0];
    const int* erow = (const int*)d_in[1];
    const int* ecol = (const int*)d_in[2];
    const float* ew = (const float*)d_in[3];
    const float* W1 = (const float*)d_in[4];
    const float* b1 = (const float*)d_in[5];
    const float* W2 = (const float*)d_in[6];
    const float* b2 = (const float*)d_in[7];
    const float* W3 = (const float*)d_in[8];
    const float* b3 = (const float*)d_in[9];
    const float* W4 = (const float*)d_in[10];
    const float* b4 = (const float*)d_in[11];
    const float* W5 = (const float*)d_in[12];
    const float* b5 = (const float*)d_in[13];

    // Output layout: log_softmax(e5), e1, e2, e3, e4, e5
    float* out0 = (float*)d_out;
    float* e1 = out0 + (size_t)NN * NCLASS;
    float* e2 = e1 + (size_t)NN * NHID;
    float* e3 = e2 + (size_t)NN * NHID;
    float* e4 = e3 + (size_t)NN * NHID;
    float* e5 = e4 + (size_t)NN * NHID;

    // Workspace layout (all 256B-aligned chunks)
    char* ws = (char*)d_ws;
    float* tmp = (float*)ws;  ws += (size_t)NN * NHID * sizeof(float);      // 12.8 MB
    float* h = (float*)ws;    ws += (size_t)NN * NHID * sizeof(float);      // 12.8 MB
    int* deg = (int*)ws;      ws += ((size_t)NN * 4 + 255) / 256 * 256;
    int* row_ptr = (int*)ws;  ws += ((size_t)(NN + 1) * 4 + 255) / 256 * 256;
    int* cursor = (int*)ws;   ws += ((size_t)NN * 4 + 255) / 256 * 256;
    int* col_s = (int*)ws;    ws += (size_t)NE * 4;                          // 3.2 MB
    float* w_s = (float*)ws;  ws += (size_t)NE * 4;                          // 3.2 MB

    // ---- CSR build (graph is identical across the 5 layers) ----
    hipMemsetAsync(deg, 0, (size_t)NN * sizeof(int), stream);
    hist_kernel<<<(NE + 255) / 256, 256, 0, stream>>>(erow, deg, NE);
    scan_kernel<<<1, 1024, 0, stream>>>(deg, row_ptr, cursor, NN);
    scatter_kernel<<<(NE + 255) / 256, 256, 0, stream>>>(erow, ecol, ew, cursor, col_s, w_s, NE);

    // ---- Layer 1: e1 = spmm(x @ W1) + b1 ; h = relu(e1) ----
    gemm_kernel<NFEAT, NHID, 4><<<NN / 16, 256, 0, stream>>>(x, W1, tmp, NN);
    spmm_kernel<NHID, true><<<NN / 4, 256, 0, stream>>>(tmp, row_ptr, col_s, w_s, b1, e1, h, NN);

    // ---- Layer 2 ----
    gemm_kernel<NHID, NHID, 4><<<NN / 16, 256, 0, stream>>>(h, W2, tmp, NN);
    spmm_kernel<NHID, true><<<NN / 4, 256, 0, stream>>>(tmp, row_ptr, col_s, w_s, b2, e2, h, NN);

    // ---- Layer 3 ----
    gemm_kernel<NHID, NHID, 4><<<NN / 16, 256, 0, stream>>>(h, W3, tmp, NN);
    spmm_kernel<NHID, true><<<NN / 4, 256, 0, stream>>>(tmp, row_ptr, col_s, w_s, b3, e3, h, NN);

    // ---- Layer 4 ----
    gemm_kernel<NHID, NHID, 4><<<NN / 16, 256, 0, stream>>>(h, W4, tmp, NN);
    spmm_kernel<NHID, true><<<NN / 4, 256, 0, stream>>>(tmp, row_ptr, col_s, w_s, b4, e4, h, NN);

    // ---- Layer 5 (no relu) ----
    gemm_kernel<NHID, NCLASS, 1><<<NN / 16, 256, 0, stream>>>(h, W5, tmp, NN);
    spmm_kernel<NCLASS, false><<<NN / 16, 256, 0, stream>>>(tmp, row_ptr, col_s, w_s, b5, e5,
                                                            nullptr, NN);

    // ---- log_softmax ----
    logsoftmax_kernel<<<(NN + 255) / 256, 256, 0, stream>>>(e5, out0, NN);
}

// Round 2
// 530.780 us; speedup vs baseline: 1.1796x; 1.1796x over previous
//
#include <hip/hip_runtime.h>
#include <math.h>

// Problem constants (from reference)
#define NN 50000
#define NE 800000
#define NFEAT 128
#define NHID 64
#define NCLASS 16
#define NB_SCAN ((NN + 255) / 256)  // 196

// ---------------- CSR build ----------------

__global__ __launch_bounds__(256) void hist_kernel(const int* __restrict__ row,
                                                   int* __restrict__ deg, int E) {
    int e = blockIdx.x * 256 + threadIdx.x;
    if (e < E) atomicAdd(&deg[row[e]], 1);
}

// Pass 1: per-block sums of deg (256 elems/block)
__global__ __launch_bounds__(256) void scan_sum_kernel(const int* __restrict__ deg,
                                                       int* __restrict__ blocksum, int n) {
    __shared__ int s[256];
    const int t = threadIdx.x;
    int i = blockIdx.x * 256 + t;
    s[t] = (i < n) ? deg[i] : 0;
    __syncthreads();
#pragma unroll
    for (int off = 128; off > 0; off >>= 1) {
        if (t < off) s[t] += s[t + off];
        __syncthreads();
    }
    if (t == 0) blocksum[blockIdx.x] = s[0];
}

// Pass 2: single block, exclusive scan of the 196 block sums (in place)
__global__ __launch_bounds__(256) void scan_top_kernel(int* __restrict__ blocksum, int nb) {
    __shared__ int s[256];
    const int t = threadIdx.x;
    int v = (t < nb) ? blocksum[t] : 0;
    s[t] = v;
    __syncthreads();
    for (int off = 1; off < 256; off <<= 1) {
        int u = (t >= off) ? s[t - off] : 0;
        __syncthreads();
        s[t] += u;
        __syncthreads();
    }
    if (t < nb) blocksum[t] = s[t] - v;  // exclusive
}

// Pass 3: per-block exclusive scan + block offset -> row_ptr, cursor
__global__ __launch_bounds__(256) void scan_final_kernel(const int* __restrict__ deg,
                                                         const int* __restrict__ blocksum,
                                                         int* __restrict__ row_ptr,
                                                         int* __restrict__ cursor, int n) {
    __shared__ int s[256];
    const int t = threadIdx.x;
    int i = blockIdx.x * 256 + t;
    int d = (i < n) ? deg[i] : 0;
    s[t] = d;
    __syncthreads();
    for (int off = 1; off < 256; off <<= 1) {
        int u = (t >= off) ? s[t - off] : 0;
        __syncthreads();
        s[t] += u;
        __syncthreads();
    }
    int excl = blocksum[blockIdx.x] + s[t] - d;
    if (i < n) {
        row_ptr[i] = excl;
        cursor[i] = excl;
        if (i == n - 1) row_ptr[n] = excl + d;
    }
}

__global__ __launch_bounds__(256) void scatter_kernel(const int* __restrict__ row,
                                                      const int* __restrict__ col,
                                                      const float* __restrict__ w,
                                                      int* __restrict__ cursor,
                                                      int* __restrict__ col_s,
                                                      float* __restrict__ w_s, int E) {
    int e = blockIdx.x * 256 + threadIdx.x;
    if (e < E) {
        int r = row[e];
        int pos = atomicAdd(&cursor[r], 1);
        col_s[pos] = col[e];
        w_s[pos] = w[e];
    }
}

// ---------------- Dense GEMM: out[M,NOUT] = in[M,K] @ W[K,NOUT] ----------------
template <int K, int NOUT, int RPT>
__global__ __launch_bounds__(256) void gemm_kernel(const float* __restrict__ in,
                                                   const float* __restrict__ Wg,
                                                   float* __restrict__ out, int M) {
    __shared__ float Wl[K * NOUT];
    for (int i = threadIdx.x * 4; i < K * NOUT; i += 256 * 4) {
        *(float4*)&Wl[i] = *(const float4*)&Wg[i];
    }
    __syncthreads();

    constexpr int GROUPS = 256 / NOUT;
    constexpr int RPB = GROUPS * RPT;
    const int col = threadIdx.x % NOUT;
    const int grp = threadIdx.x / NOUT;
    const int r = blockIdx.x * RPB + grp * RPT;
    if (r >= M) return;

    float acc[RPT];
#pragma unroll
    for (int j = 0; j < RPT; j++) acc[j] = 0.f;

    const float* pr = in + (size_t)r * K;
#pragma unroll 2
    for (int k = 0; k < K; k += 4) {
        float w0 = Wl[(k + 0) * NOUT + col];
        float w1 = Wl[(k + 1) * NOUT + col];
        float w2 = Wl[(k + 2) * NOUT + col];
        float w3 = Wl[(k + 3) * NOUT + col];
#pragma unroll
        for (int j = 0; j < RPT; j++) {
            float4 xv = *(const float4*)(pr + j * K + k);
            acc[j] += xv.x * w0;
            acc[j] += xv.y * w1;
            acc[j] += xv.z * w2;
            acc[j] += xv.w * w3;
        }
    }
#pragma unroll
    for (int j = 0; j < RPT; j++) {
        out[(size_t)(r + j) * NOUT + col] = acc[j];
    }
}

// ---------------- SpMM (F=64): e_out = A @ tmp + bias ; h_out = relu ----------------
template <int F, bool RELU>
__global__ __launch_bounds__(256) void spmm_kernel(const float* __restrict__ tmp,
                                                   const int* __restrict__ row_ptr,
                                                   const int* __restrict__ col_s,
                                                   const float* __restrict__ w_s,
                                                   const float* __restrict__ bias,
                                                   float* __restrict__ e_out,
                                                   float* __restrict__ h_out, int M) {
    constexpr int RPB = 256 / F;
    const int f = threadIdx.x % F;
    const int rl = threadIdx.x / F;
    const int r = blockIdx.x * RPB + rl;
    if (r >= M) return;

    const int start = row_ptr[r];
    const int end = row_ptr[r + 1];
    float acc = 0.f;
    int e = start;
    for (; e + 3 < end; e += 4) {
        int c0 = col_s[e + 0], c1 = col_s[e + 1], c2 = col_s[e + 2], c3 = col_s[e + 3];
        float w0 = w_s[e + 0], w1 = w_s[e + 1], w2 = w_s[e + 2], w3 = w_s[e + 3];
        acc += w0 * tmp[(size_t)c0 * F + f];
        acc += w1 * tmp[(size_t)c1 * F + f];
        acc += w2 * tmp[(size_t)c2 * F + f];
        acc += w3 * tmp[(size_t)c3 * F + f];
    }
    for (; e < end; e++) {
        acc += w_s[e] * tmp[(size_t)col_s[e] * F + f];
    }
    float v = acc + bias[f];
    e_out[(size_t)r * F + f] = v;
    if (RELU) h_out[(size_t)r * F + f] = fmaxf(v, 0.f);
}

// ---------------- SpMM (F=16) fused with log_softmax ----------------
// 16 lanes per row hold the 16 classes; group-of-16 shuffle reductions.
__global__ __launch_bounds__(256) void spmm16_lsm_kernel(const float* __restrict__ tmp,
                                                         const int* __restrict__ row_ptr,
                                                         const int* __restrict__ col_s,
                                                         const float* __restrict__ w_s,
                                                         const float* __restrict__ bias,
                                                         float* __restrict__ e5,
                                                         float* __restrict__ out0, int M) {
    const int f = threadIdx.x & 15;
    const int rl = threadIdx.x >> 4;
    const int r = blockIdx.x * 16 + rl;
    if (r >= M) return;

    const int start = row_ptr[r];
    const int end = row_ptr[r + 1];
    float acc = 0.f;
    int e = start;
    for (; e + 3 < end; e += 4) {
        int c0 = col_s[e + 0], c1 = col_s[e + 1], c2 = col_s[e + 2], c3 = col_s[e + 3];
        float w0 = w_s[e + 0], w1 = w_s[e + 1], w2 = w_s[e + 2], w3 = w_s[e + 3];
        acc += w0 * tmp[(size_t)c0 * 16 + f];
        acc += w1 * tmp[(size_t)c1 * 16 + f];
        acc += w2 * tmp[(size_t)c2 * 16 + f];
        acc += w3 * tmp[(size_t)c3 * 16 + f];
    }
    for (; e < end; e++) {
        acc += w_s[e] * tmp[(size_t)col_s[e] * 16 + f];
    }
    float v = acc + bias[f];
    e5[(size_t)r * 16 + f] = v;

    float m = v;
#pragma unroll
    for (int off = 1; off < 16; off <<= 1) m = fmaxf(m, __shfl_xor(m, off, 16));
    float s = expf(v - m);
#pragma unroll
    for (int off = 1; off < 16; off <<= 1) s += __shfl_xor(s, off, 16);
    float ls = logf(s);
    out0[(size_t)r * 16 + f] = v - m - ls;
}

// ---------------- launch ----------------

extern "C" void kernel_launch(void* const* d_in, const int* in_sizes, int n_in,
                              void* d_out, int out_size, void* d_ws, size_t ws_size,
                              hipStream_t stream) {
    const float* x = (const float*)d_in[0];
    const int* erow = (const int*)d_in[1];
    const int* ecol = (const int*)d_in[2];
    const float* ew = (const float*)d_in[3];
    const float* W1 = (const float*)d_in[4];
    const float* b1 = (const float*)d_in[5];
    const float* W2 = (const float*)d_in[6];
    const float* b2 = (const float*)d_in[7];
    const float* W3 = (const float*)d_in[8];
    const float* b3 = (const float*)d_in[9];
    const float* W4 = (const float*)d_in[10];
    const float* b4 = (const float*)d_in[11];
    const float* W5 = (const float*)d_in[12];
    const float* b5 = (const float*)d_in[13];

    // Output layout: log_softmax(e5), e1, e2, e3, e4, e5
    float* out0 = (float*)d_out;
    float* e1 = out0 + (size_t)NN * NCLASS;
    float* e2 = e1 + (size_t)NN * NHID;
    float* e3 = e2 + (size_t)NN * NHID;
    float* e4 = e3 + (size_t)NN * NHID;
    float* e5 = e4 + (size_t)NN * NHID;

    // Workspace layout
    char* ws = (char*)d_ws;
    float* tmp = (float*)ws;  ws += (size_t)NN * NHID * sizeof(float);
    float* h = (float*)ws;    ws += (size_t)NN * NHID * sizeof(float);
    int* deg = (int*)ws;      ws += ((size_t)NN * 4 + 255) / 256 * 256;
    int* row_ptr = (int*)ws;  ws += ((size_t)(NN + 1) * 4 + 255) / 256 * 256;
    int* cursor = (int*)ws;   ws += ((size_t)NN * 4 + 255) / 256 * 256;
    int* blocksum = (int*)ws; ws += ((size_t)NB_SCAN * 4 + 255) / 256 * 256;
    int* col_s = (int*)ws;    ws += (size_t)NE * 4;
    float* w_s = (float*)ws;  ws += (size_t)NE * 4;

    // ---- CSR build ----
    hipMemsetAsync(deg, 0, (size_t)NN * sizeof(int), stream);
    hist_kernel<<<(NE + 255) / 256, 256, 0, stream>>>(erow, deg, NE);
    scan_sum_kernel<<<NB_SCAN, 256, 0, stream>>>(deg, blocksum, NN);
    scan_top_kernel<<<1, 256, 0, stream>>>(blocksum, NB_SCAN);
    scan_final_kernel<<<NB_SCAN, 256, 0, stream>>>(deg, blocksum, row_ptr, cursor, NN);
    scatter_kernel<<<(NE + 255) / 256, 256, 0, stream>>>(erow, ecol, ew, cursor, col_s, w_s, NE);

    // ---- Layer 1 ----
    gemm_kernel<NFEAT, NHID, 4><<<NN / 16, 256, 0, stream>>>(x, W1, tmp, NN);
    spmm_kernel<NHID, true><<<NN / 4, 256, 0, stream>>>(tmp, row_ptr, col_s, w_s, b1, e1, h, NN);

    // ---- Layer 2 ----
    gemm_kernel<NHID, NHID, 4><<<NN / 16, 256, 0, stream>>>(h, W2, tmp, NN);
    spmm_kernel<NHID, true><<<NN / 4, 256, 0, stream>>>(tmp, row_ptr, col_s, w_s, b2, e2, h, NN);

    // ---- Layer 3 ----
    gemm_kernel<NHID, NHID, 4><<<NN / 16, 256, 0, stream>>>(h, W3, tmp, NN);
    spmm_kernel<NHID, true><<<NN / 4, 256, 0, stream>>>(tmp, row_ptr, col_s, w_s, b3, e3, h, NN);

    // ---- Layer 4 ----
    gemm_kernel<NHID, NHID, 4><<<NN / 16, 256, 0, stream>>>(h, W4, tmp, NN);
    spmm_kernel<NHID, true><<<NN / 4, 256, 0, stream>>>(tmp, row_ptr, col_s, w_s, b4, e4, h, NN);

    // ---- Layer 5: GEMM -> SpMM fused with log_softmax ----
    gemm_kernel<NHID, NCLASS, 1><<<NN / 16, 256, 0, stream>>>(h, W5, tmp, NN);
    spmm16_lsm_kernel<<<(NN + 15) / 16, 256, 0, stream>>>(tmp, row_ptr, col_s, w_s, b5, e5,
                                                          out0, NN);
}

// Round 3
// 448.123 us; speedup vs baseline: 1.3971x; 1.1845x over previous
//
#include <hip/hip_runtime.h>
#include <math.h>

// Problem constants (from reference)
#define NN 50000
#define NE 800000
#define NFEAT 128
#define NHID 64
#define NCLASS 16
#define NB_SCAN ((NN + 255) / 256)  // 196

struct alignas(8) Edge {
    int c;
    float w;
};

// ---------------- CSR build ----------------

__global__ __launch_bounds__(256) void hist_kernel(const int* __restrict__ row,
                                                   int* __restrict__ deg, int E) {
    int e = blockIdx.x * 256 + threadIdx.x;
    if (e < E) atomicAdd(&deg[row[e]], 1);
}

__global__ __launch_bounds__(256) void scan_sum_kernel(const int* __restrict__ deg,
                                                       int* __restrict__ blocksum, int n) {
    __shared__ int s[256];
    const int t = threadIdx.x;
    int i = blockIdx.x * 256 + t;
    s[t] = (i < n) ? deg[i] : 0;
    __syncthreads();
#pragma unroll
    for (int off = 128; off > 0; off >>= 1) {
        if (t < off) s[t] += s[t + off];
        __syncthreads();
    }
    if (t == 0) blocksum[blockIdx.x] = s[0];
}

__global__ __launch_bounds__(256) void scan_top_kernel(int* __restrict__ blocksum, int nb) {
    __shared__ int s[256];
    const int t = threadIdx.x;
    int v = (t < nb) ? blocksum[t] : 0;
    s[t] = v;
    __syncthreads();
    for (int off = 1; off < 256; off <<= 1) {
        int u = (t >= off) ? s[t - off] : 0;
        __syncthreads();
        s[t] += u;
        __syncthreads();
    }
    if (t < nb) blocksum[t] = s[t] - v;  // exclusive
}

__global__ __launch_bounds__(256) void scan_final_kernel(const int* __restrict__ deg,
                                                         const int* __restrict__ blocksum,
                                                         int* __restrict__ row_ptr,
                                                         int* __restrict__ cursor, int n) {
    __shared__ int s[256];
    const int t = threadIdx.x;
    int i = blockIdx.x * 256 + t;
    int d = (i < n) ? deg[i] : 0;
    s[t] = d;
    __syncthreads();
    for (int off = 1; off < 256; off <<= 1) {
        int u = (t >= off) ? s[t - off] : 0;
        __syncthreads();
        s[t] += u;
        __syncthreads();
    }
    int excl = blocksum[blockIdx.x] + s[t] - d;
    if (i < n) {
        row_ptr[i] = excl;
        cursor[i] = excl;
        if (i == n - 1) row_ptr[n] = excl + d;
    }
}

// Single 8B store per edge: halves write-allocate traffic vs two 4B streams.
__global__ __launch_bounds__(256) void scatter_kernel(const int* __restrict__ row,
                                                      const int* __restrict__ col,
                                                      const float* __restrict__ w,
                                                      int* __restrict__ cursor,
                                                      Edge* __restrict__ pairs, int E) {
    int e = blockIdx.x * 256 + threadIdx.x;
    if (e < E) {
        int r = row[e];
        int pos = atomicAdd(&cursor[r], 1);
        Edge p;
        p.c = col[e];
        p.w = w[e];
        pairs[pos] = p;
    }
}

// ---------------- Tiled GEMM: out[M,64] = in[M,K] @ W[K,64] ----------------
// 64x64 block tile, 256 threads as 16x16 grid, each computes a 4x4 micro-tile.
// x staged transposed in LDS (stride 68: 16B-aligned rows, conflict-light),
// W chunk staged row-major. 16 FMA per 2x ds_read_b128.
template <int K>
__global__ __launch_bounds__(256) void gemm64_kernel(const float* __restrict__ in,
                                                     const float* __restrict__ Wg,
                                                     float* __restrict__ out, int M) {
    constexpr int KC = 64;
    __shared__ float xs[KC][68];
    __shared__ float Ws[KC][64];
    const int t = threadIdx.x;
    const int tx = t % 16;  // col group: cols tx*4..tx*4+3
    const int ty = t / 16;  // row group: rows ty*4..ty*4+3
    const int r0 = blockIdx.x * 64;

    float acc[4][4];
#pragma unroll
    for (int i = 0; i < 4; i++)
#pragma unroll
        for (int j = 0; j < 4; j++) acc[i][j] = 0.f;

    for (int k0 = 0; k0 < K; k0 += KC) {
        // stage W chunk (KC*64 floats)
        for (int i = t * 4; i < KC * 64; i += 1024) {
            *(float4*)&Ws[i / 64][i % 64] = *(const float4*)&Wg[(size_t)k0 * 64 + i];
        }
        // stage x chunk transposed: thread t -> row t/4, k-quad t%4 (16 floats)
        {
            const int r = t / 4;
            const int q = t % 4;
            const int gr = r0 + r;
#pragma unroll
            for (int i = 0; i < 4; i++) {
                int k = q * 16 + i * 4;
                float4 v;
                if (gr < M)
                    v = *(const float4*)&in[(size_t)gr * K + k0 + k];
                else
                    v = make_float4(0.f, 0.f, 0.f, 0.f);
                xs[k + 0][r] = v.x;
                xs[k + 1][r] = v.y;
                xs[k + 2][r] = v.z;
                xs[k + 3][r] = v.w;
            }
        }
        __syncthreads();
#pragma unroll 8
        for (int k = 0; k < KC; k++) {
            float4 xv = *(const float4*)&xs[k][ty * 4];
            float4 wv = *(const float4*)&Ws[k][tx * 4];
            acc[0][0] += xv.x * wv.x; acc[0][1] += xv.x * wv.y;
            acc[0][2] += xv.x * wv.z; acc[0][3] += xv.x * wv.w;
            acc[1][0] += xv.y * wv.x; acc[1][1] += xv.y * wv.y;
            acc[1][2] += xv.y * wv.z; acc[1][3] += xv.y * wv.w;
            acc[2][0] += xv.z * wv.x; acc[2][1] += xv.z * wv.y;
            acc[2][2] += xv.z * wv.z; acc[2][3] += xv.z * wv.w;
            acc[3][0] += xv.w * wv.x; acc[3][1] += xv.w * wv.y;
            acc[3][2] += xv.w * wv.z; acc[3][3] += xv.w * wv.w;
        }
        __syncthreads();
    }
#pragma unroll
    for (int i = 0; i < 4; i++) {
        int r = r0 + ty * 4 + i;
        if (r < M) {
            float4 v;
            v.x = acc[i][0]; v.y = acc[i][1]; v.z = acc[i][2]; v.w = acc[i][3];
            *(float4*)&out[(size_t)r * 64 + tx * 4] = v;
        }
    }
}

// ---------------- Small GEMM (layer 5): out[M,16] = in[M,64] @ W[64,16] ----------------
template <int K, int NOUT, int RPT>
__global__ __launch_bounds__(256) void gemm_kernel(const float* __restrict__ in,
                                                   const float* __restrict__ Wg,
                                                   float* __restrict__ out, int M) {
    __shared__ float Wl[K * NOUT];
    for (int i = threadIdx.x * 4; i < K * NOUT; i += 256 * 4) {
        *(float4*)&Wl[i] = *(const float4*)&Wg[i];
    }
    __syncthreads();

    constexpr int GROUPS = 256 / NOUT;
    constexpr int RPB = GROUPS * RPT;
    const int col = threadIdx.x % NOUT;
    const int grp = threadIdx.x / NOUT;
    const int r = blockIdx.x * RPB + grp * RPT;
    if (r >= M) return;

    float acc[RPT];
#pragma unroll
    for (int j = 0; j < RPT; j++) acc[j] = 0.f;

    const float* pr = in + (size_t)r * K;
#pragma unroll 2
    for (int k = 0; k < K; k += 4) {
        float w0 = Wl[(k + 0) * NOUT + col];
        float w1 = Wl[(k + 1) * NOUT + col];
        float w2 = Wl[(k + 2) * NOUT + col];
        float w3 = Wl[(k + 3) * NOUT + col];
#pragma unroll
        for (int j = 0; j < RPT; j++) {
            float4 xv = *(const float4*)(pr + j * K + k);
            acc[j] += xv.x * w0;
            acc[j] += xv.y * w1;
            acc[j] += xv.z * w2;
            acc[j] += xv.w * w3;
        }
    }
#pragma unroll
    for (int j = 0; j < RPT; j++) {
        if (r + j < M) out[(size_t)(r + j) * NOUT + col] = acc[j];
    }
}

// ---------------- SpMM (F=64): e_out = A @ tmp + bias ; h_out = relu ----------------
template <int F, bool RELU>
__global__ __launch_bounds__(256) void spmm_kernel(const float* __restrict__ tmp,
                                                   const int* __restrict__ row_ptr,
                                                   const Edge* __restrict__ pairs,
                                                   const float* __restrict__ bias,
                                                   float* __restrict__ e_out,
                                                   float* __restrict__ h_out, int M) {
    constexpr int RPB = 256 / F;
    const int f = threadIdx.x % F;
    const int rl = threadIdx.x / F;
    const int r = blockIdx.x * RPB + rl;
    if (r >= M) return;

    const int start = row_ptr[r];
    const int end = row_ptr[r + 1];
    float acc = 0.f;
    int e = start;
    for (; e + 3 < end; e += 4) {
        Edge p0 = pairs[e + 0], p1 = pairs[e + 1], p2 = pairs[e + 2], p3 = pairs[e + 3];
        acc += p0.w * tmp[(size_t)p0.c * F + f];
        acc += p1.w * tmp[(size_t)p1.c * F + f];
        acc += p2.w * tmp[(size_t)p2.c * F + f];
        acc += p3.w * tmp[(size_t)p3.c * F + f];
    }
    for (; e < end; e++) {
        Edge p = pairs[e];
        acc += p.w * tmp[(size_t)p.c * F + f];
    }
    float v = acc + bias[f];
    e_out[(size_t)r * F + f] = v;
    if (RELU) h_out[(size_t)r * F + f] = fmaxf(v, 0.f);
}

// ---------------- SpMM (F=16) fused with log_softmax ----------------
__global__ __launch_bounds__(256) void spmm16_lsm_kernel(const float* __restrict__ tmp,
                                                         const int* __restrict__ row_ptr,
                                                         const Edge* __restrict__ pairs,
                                                         const float* __restrict__ bias,
                                                         float* __restrict__ e5,
                                                         float* __restrict__ out0, int M) {
    const int f = threadIdx.x & 15;
    const int rl = threadIdx.x >> 4;
    const int r = blockIdx.x * 16 + rl;
    if (r >= M) return;

    const int start = row_ptr[r];
    const int end = row_ptr[r + 1];
    float acc = 0.f;
    int e = start;
    for (; e + 3 < end; e += 4) {
        Edge p0 = pairs[e + 0], p1 = pairs[e + 1], p2 = pairs[e + 2], p3 = pairs[e + 3];
        acc += p0.w * tmp[(size_t)p0.c * 16 + f];
        acc += p1.w * tmp[(size_t)p1.c * 16 + f];
        acc += p2.w * tmp[(size_t)p2.c * 16 + f];
        acc += p3.w * tmp[(size_t)p3.c * 16 + f];
    }
    for (; e < end; e++) {
        Edge p = pairs[e];
        acc += p.w * tmp[(size_t)p.c * 16 + f];
    }
    float v = acc + bias[f];
    e5[(size_t)r * 16 + f] = v;

    float m = v;
#pragma unroll
    for (int off = 1; off < 16; off <<= 1) m = fmaxf(m, __shfl_xor(m, off, 16));
    float s = expf(v - m);
#pragma unroll
    for (int off = 1; off < 16; off <<= 1) s += __shfl_xor(s, off, 16);
    float ls = logf(s);
    out0[(size_t)r * 16 + f] = v - m - ls;
}

// ---------------- launch ----------------

extern "C" void kernel_launch(void* const* d_in, const int* in_sizes, int n_in,
                              void* d_out, int out_size, void* d_ws, size_t ws_size,
                              hipStream_t stream) {
    const float* x = (const float*)d_in[0];
    const int* erow = (const int*)d_in[1];
    const int* ecol = (const int*)d_in[2];
    const float* ew = (const float*)d_in[3];
    const float* W1 = (const float*)d_in[4];
    const float* b1 = (const float*)d_in[5];
    const float* W2 = (const float*)d_in[6];
    const float* b2 = (const float*)d_in[7];
    const float* W3 = (const float*)d_in[8];
    const float* b3 = (const float*)d_in[9];
    const float* W4 = (const float*)d_in[10];
    const float* b4 = (const float*)d_in[11];
    const float* W5 = (const float*)d_in[12];
    const float* b5 = (const float*)d_in[13];

    // Output layout: log_softmax(e5), e1, e2, e3, e4, e5
    float* out0 = (float*)d_out;
    float* e1 = out0 + (size_t)NN * NCLASS;
    float* e2 = e1 + (size_t)NN * NHID;
    float* e3 = e2 + (size_t)NN * NHID;
    float* e4 = e3 + (size_t)NN * NHID;
    float* e5 = e4 + (size_t)NN * NHID;

    // Workspace layout
    char* ws = (char*)d_ws;
    float* tmp = (float*)ws;  ws += (size_t)NN * NHID * sizeof(float);
    float* h = (float*)ws;    ws += (size_t)NN * NHID * sizeof(float);
    int* deg = (int*)ws;      ws += ((size_t)NN * 4 + 255) / 256 * 256;
    int* row_ptr = (int*)ws;  ws += ((size_t)(NN + 1) * 4 + 255) / 256 * 256;
    int* cursor = (int*)ws;   ws += ((size_t)NN * 4 + 255) / 256 * 256;
    int* blocksum = (int*)ws; ws += ((size_t)NB_SCAN * 4 + 255) / 256 * 256;
    Edge* pairs = (Edge*)ws;  ws += (size_t)NE * sizeof(Edge);

    const int GB = (NN + 63) / 64;  // 782 tile-GEMM blocks

    // ---- CSR build ----
    hipMemsetAsync(deg, 0, (size_t)NN * sizeof(int), stream);
    hist_kernel<<<(NE + 255) / 256, 256, 0, stream>>>(erow, deg, NE);
    scan_sum_kernel<<<NB_SCAN, 256, 0, stream>>>(deg, blocksum, NN);
    scan_top_kernel<<<1, 256, 0, stream>>>(blocksum, NB_SCAN);
    scan_final_kernel<<<NB_SCAN, 256, 0, stream>>>(deg, blocksum, row_ptr, cursor, NN);
    scatter_kernel<<<(NE + 255) / 256, 256, 0, stream>>>(erow, ecol, ew, cursor, pairs, NE);

    // ---- Layer 1 ----
    gemm64_kernel<NFEAT><<<GB, 256, 0, stream>>>(x, W1, tmp, NN);
    spmm_kernel<NHID, true><<<NN / 4, 256, 0, stream>>>(tmp, row_ptr, pairs, b1, e1, h, NN);

    // ---- Layer 2 ----
    gemm64_kernel<NHID><<<GB, 256, 0, stream>>>(h, W2, tmp, NN);
    spmm_kernel<NHID, true><<<NN / 4, 256, 0, stream>>>(tmp, row_ptr, pairs, b2, e2, h, NN);

    // ---- Layer 3 ----
    gemm64_kernel<NHID><<<GB, 256, 0, stream>>>(h, W3, tmp, NN);
    spmm_kernel<NHID, true><<<NN / 4, 256, 0, stream>>>(tmp, row_ptr, pairs, b3, e3, h, NN);

    // ---- Layer 4 ----
    gemm64_kernel<NHID><<<GB, 256, 0, stream>>>(h, W4, tmp, NN);
    spmm_kernel<NHID, true><<<NN / 4, 256, 0, stream>>>(tmp, row_ptr, pairs, b4, e4, h, NN);

    // ---- Layer 5: GEMM -> SpMM fused with log_softmax ----
    gemm_kernel<NHID, NCLASS, 4><<<GB, 256, 0, stream>>>(h, W5, tmp, NN);
    spmm16_lsm_kernel<<<(NN + 15) / 16, 256, 0, stream>>>(tmp, row_ptr, pairs, b5, e5, out0, NN);
}

// Round 4
// 396.289 us; speedup vs baseline: 1.5799x; 1.1308x over previous
//
#include <hip/hip_runtime.h>
#include <math.h>

// Problem constants (from reference)
#define NN 50000
#define NE 800000
#define NFEAT 128
#define NHID 64
#define NCLASS 16
#define NB_SCAN ((NN + 255) / 256)  // 196
#define ROWS_PER_GRP 6250           // NN / 8 XCD groups
#define SCHUNKS 392                 // scatter edge chunks; grid = 8*392 = 3136 blocks

struct alignas(8) Edge {
    int c;
    float w;
};

// fp32 <-> bf16 helpers (RNE round)
__device__ inline unsigned short f2bf(float f) {
    unsigned u = __builtin_bit_cast(unsigned, f);
    u += 0x7fffu + ((u >> 16) & 1u);
    return (unsigned short)(u >> 16);
}
__device__ inline float bf2f(unsigned short h) {
    return __builtin_bit_cast(float, (unsigned)h << 16);
}

// ---------------- CSR build ----------------

__global__ __launch_bounds__(256) void hist_kernel(const int* __restrict__ row,
                                                   int* __restrict__ deg, int E) {
    int e = blockIdx.x * 256 + threadIdx.x;
    if (e < E) atomicAdd(&deg[row[e]], 1);
}

__global__ __launch_bounds__(256) void scan_sum_kernel(const int* __restrict__ deg,
                                                       int* __restrict__ blocksum, int n) {
    __shared__ int s[256];
    const int t = threadIdx.x;
    int i = blockIdx.x * 256 + t;
    s[t] = (i < n) ? deg[i] : 0;
    __syncthreads();
#pragma unroll
    for (int off = 128; off > 0; off >>= 1) {
        if (t < off) s[t] += s[t + off];
        __syncthreads();
    }
    if (t == 0) blocksum[blockIdx.x] = s[0];
}

__global__ __launch_bounds__(256) void scan_top_kernel(int* __restrict__ blocksum, int nb) {
    __shared__ int s[256];
    const int t = threadIdx.x;
    int v = (t < nb) ? blocksum[t] : 0;
    s[t] = v;
    __syncthreads();
    for (int off = 1; off < 256; off <<= 1) {
        int u = (t >= off) ? s[t - off] : 0;
        __syncthreads();
        s[t] += u;
        __syncthreads();
    }
    if (t < nb) blocksum[t] = s[t] - v;  // exclusive
}

__global__ __launch_bounds__(256) void scan_final_kernel(const int* __restrict__ deg,
                                                         const int* __restrict__ blocksum,
                                                         int* __restrict__ row_ptr,
                                                         int* __restrict__ cursor, int n) {
    __shared__ int s[256];
    const int t = threadIdx.x;
    int i = blockIdx.x * 256 + t;
    int d = (i < n) ? deg[i] : 0;
    s[t] = d;
    __syncthreads();
    for (int off = 1; off < 256; off <<= 1) {
        int u = (t >= off) ? s[t - off] : 0;
        __syncthreads();
        s[t] += u;
        __syncthreads();
    }
    int excl = blocksum[blockIdx.x] + s[t] - d;
    if (i < n) {
        row_ptr[i] = excl;
        cursor[i] = excl;
        if (i == n - 1) row_ptr[n] = excl + d;
    }
}

// XCD-partitioned scatter: block b -> row group b%8 (round-robin blockIdx->XCD),
// edge chunk b/8. Each XCD's destination slice (~0.8 MB of CSR) stays L2-resident
// and lines fill completely before a single full-line eviction.
__global__ __launch_bounds__(256) void scatter_part_kernel(const int* __restrict__ row,
                                                           const int* __restrict__ col,
                                                           const float* __restrict__ w,
                                                           int* __restrict__ cursor,
                                                           Edge* __restrict__ pairs, int E) {
    const int g = blockIdx.x & 7;
    const int chunk = blockIdx.x >> 3;
    const int CH = (E + SCHUNKS - 1) / SCHUNKS;
    const int lo = chunk * CH;
    const int hi = (lo + CH < E) ? lo + CH : E;
    for (int e = lo + threadIdx.x; e < hi; e += 256) {
        int r = row[e];
        if (r / ROWS_PER_GRP == g) {
            int pos = atomicAdd(&cursor[r], 1);
            Edge p;
            p.c = col[e];
            p.w = w[e];
            pairs[pos] = p;
        }
    }
}

// ---------------- Tiled GEMM: out[M,64] = in[M,K] @ W[K,64] ----------------
// 64x64 tile, 256 threads as 16x16, 4x4 micro-tile each. Optional bf16 output.
template <int K, bool BF16OUT>
__global__ __launch_bounds__(256) void gemm64_kernel(const float* __restrict__ in,
                                                     const float* __restrict__ Wg,
                                                     void* __restrict__ outv, int M) {
    constexpr int KC = 64;
    __shared__ float xs[KC][68];
    __shared__ float Ws[KC][64];
    const int t = threadIdx.x;
    const int tx = t % 16;
    const int ty = t / 16;
    const int r0 = blockIdx.x * 64;

    float acc[4][4];
#pragma unroll
    for (int i = 0; i < 4; i++)
#pragma unroll
        for (int j = 0; j < 4; j++) acc[i][j] = 0.f;

    for (int k0 = 0; k0 < K; k0 += KC) {
        for (int i = t * 4; i < KC * 64; i += 1024) {
            *(float4*)&Ws[i / 64][i % 64] = *(const float4*)&Wg[(size_t)k0 * 64 + i];
        }
        {
            const int r = t / 4;
            const int q = t % 4;
            const int gr = r0 + r;
#pragma unroll
            for (int i = 0; i < 4; i++) {
                int k = q * 16 + i * 4;
                float4 v;
                if (gr < M)
                    v = *(const float4*)&in[(size_t)gr * K + k0 + k];
                else
                    v = make_float4(0.f, 0.f, 0.f, 0.f);
                xs[k + 0][r] = v.x;
                xs[k + 1][r] = v.y;
                xs[k + 2][r] = v.z;
                xs[k + 3][r] = v.w;
            }
        }
        __syncthreads();
#pragma unroll 8
        for (int k = 0; k < KC; k++) {
            float4 xv = *(const float4*)&xs[k][ty * 4];
            float4 wv = *(const float4*)&Ws[k][tx * 4];
            acc[0][0] += xv.x * wv.x; acc[0][1] += xv.x * wv.y;
            acc[0][2] += xv.x * wv.z; acc[0][3] += xv.x * wv.w;
            acc[1][0] += xv.y * wv.x; acc[1][1] += xv.y * wv.y;
            acc[1][2] += xv.y * wv.z; acc[1][3] += xv.y * wv.w;
            acc[2][0] += xv.z * wv.x; acc[2][1] += xv.z * wv.y;
            acc[2][2] += xv.z * wv.z; acc[2][3] += xv.z * wv.w;
            acc[3][0] += xv.w * wv.x; acc[3][1] += xv.w * wv.y;
            acc[3][2] += xv.w * wv.z; acc[3][3] += xv.w * wv.w;
        }
        __syncthreads();
    }
#pragma unroll
    for (int i = 0; i < 4; i++) {
        int r = r0 + ty * 4 + i;
        if (r < M) {
            if (BF16OUT) {
                ushort4 u;
                u.x = f2bf(acc[i][0]);
                u.y = f2bf(acc[i][1]);
                u.z = f2bf(acc[i][2]);
                u.w = f2bf(acc[i][3]);
                *(ushort4*)&((unsigned short*)outv)[(size_t)r * 64 + tx * 4] = u;
            } else {
                float4 v;
                v.x = acc[i][0]; v.y = acc[i][1]; v.z = acc[i][2]; v.w = acc[i][3];
                *(float4*)&((float*)outv)[(size_t)r * 64 + tx * 4] = v;
            }
        }
    }
}

// ---------------- Small GEMM (layer 5): out[M,16] = in[M,64] @ W[64,16] ----------------
template <int K, int NOUT, int RPT>
__global__ __launch_bounds__(256) void gemm_kernel(const float* __restrict__ in,
                                                   const float* __restrict__ Wg,
                                                   float* __restrict__ out, int M) {
    __shared__ float Wl[K * NOUT];
    for (int i = threadIdx.x * 4; i < K * NOUT; i += 256 * 4) {
        *(float4*)&Wl[i] = *(const float4*)&Wg[i];
    }
    __syncthreads();

    constexpr int GROUPS = 256 / NOUT;
    constexpr int RPB = GROUPS * RPT;
    const int col = threadIdx.x % NOUT;
    const int grp = threadIdx.x / NOUT;
    const int r = blockIdx.x * RPB + grp * RPT;
    if (r >= M) return;

    float acc[RPT];
#pragma unroll
    for (int j = 0; j < RPT; j++) acc[j] = 0.f;

    const float* pr = in + (size_t)r * K;
#pragma unroll 2
    for (int k = 0; k < K; k += 4) {
        float w0 = Wl[(k + 0) * NOUT + col];
        float w1 = Wl[(k + 1) * NOUT + col];
        float w2 = Wl[(k + 2) * NOUT + col];
        float w3 = Wl[(k + 3) * NOUT + col];
#pragma unroll
        for (int j = 0; j < RPT; j++) {
            float4 xv = *(const float4*)(pr + j * K + k);
            acc[j] += xv.x * w0;
            acc[j] += xv.y * w1;
            acc[j] += xv.z * w2;
            acc[j] += xv.w * w3;
        }
    }
#pragma unroll
    for (int j = 0; j < RPT; j++) {
        if (r + j < M) out[(size_t)(r + j) * NOUT + col] = acc[j];
    }
}

// ---------------- SpMM (F=64, bf16 gather): e = A @ tmpb + bias ; h = relu ----------------
// One wave per row (64 lanes = 64 features). Row bounds scalarized.
template <bool RELU>
__global__ __launch_bounds__(256) void spmm64b_kernel(const unsigned short* __restrict__ tmpb,
                                                      const int* __restrict__ row_ptr,
                                                      const Edge* __restrict__ pairs,
                                                      const float* __restrict__ bias,
                                                      float* __restrict__ e_out,
                                                      float* __restrict__ h_out, int M) {
    const int f = threadIdx.x & 63;
    const int rl = threadIdx.x >> 6;
    const int r = blockIdx.x * 4 + rl;
    if (r >= M) return;

    const int start = __builtin_amdgcn_readfirstlane(row_ptr[r]);
    const int end = __builtin_amdgcn_readfirstlane(row_ptr[r + 1]);
    float acc = 0.f;
    int e = start;
    for (; e + 3 < end; e += 4) {
        Edge p0 = pairs[e + 0], p1 = pairs[e + 1], p2 = pairs[e + 2], p3 = pairs[e + 3];
        acc += p0.w * bf2f(tmpb[(size_t)p0.c * 64 + f]);
        acc += p1.w * bf2f(tmpb[(size_t)p1.c * 64 + f]);
        acc += p2.w * bf2f(tmpb[(size_t)p2.c * 64 + f]);
        acc += p3.w * bf2f(tmpb[(size_t)p3.c * 64 + f]);
    }
    for (; e < end; e++) {
        Edge p = pairs[e];
        acc += p.w * bf2f(tmpb[(size_t)p.c * 64 + f]);
    }
    float v = acc + bias[f];
    e_out[(size_t)r * 64 + f] = v;
    if (RELU) h_out[(size_t)r * 64 + f] = fmaxf(v, 0.f);
}

// ---------------- SpMM (F=16, fp32) fused with log_softmax ----------------
__global__ __launch_bounds__(256) void spmm16_lsm_kernel(const float* __restrict__ tmp,
                                                         const int* __restrict__ row_ptr,
                                                         const Edge* __restrict__ pairs,
                                                         const float* __restrict__ bias,
                                                         float* __restrict__ e5,
                                                         float* __restrict__ out0, int M) {
    const int f = threadIdx.x & 15;
    const int rl = threadIdx.x >> 4;
    const int r = blockIdx.x * 16 + rl;
    if (r >= M) return;

    const int start = row_ptr[r];
    const int end = row_ptr[r + 1];
    float acc = 0.f;
    int e = start;
    for (; e + 3 < end; e += 4) {
        Edge p0 = pairs[e + 0], p1 = pairs[e + 1], p2 = pairs[e + 2], p3 = pairs[e + 3];
        acc += p0.w * tmp[(size_t)p0.c * 16 + f];
        acc += p1.w * tmp[(size_t)p1.c * 16 + f];
        acc += p2.w * tmp[(size_t)p2.c * 16 + f];
        acc += p3.w * tmp[(size_t)p3.c * 16 + f];
    }
    for (; e < end; e++) {
        Edge p = pairs[e];
        acc += p.w * tmp[(size_t)p.c * 16 + f];
    }
    float v = acc + bias[f];
    e5[(size_t)r * 16 + f] = v;

    float m = v;
#pragma unroll
    for (int off = 1; off < 16; off <<= 1) m = fmaxf(m, __shfl_xor(m, off, 16));
    float s = expf(v - m);
#pragma unroll
    for (int off = 1; off < 16; off <<= 1) s += __shfl_xor(s, off, 16);
    float ls = logf(s);
    out0[(size_t)r * 16 + f] = v - m - ls;
}

// ---------------- launch ----------------

extern "C" void kernel_launch(void* const* d_in, const int* in_sizes, int n_in,
                              void* d_out, int out_size, void* d_ws, size_t ws_size,
                              hipStream_t stream) {
    const float* x = (const float*)d_in[0];
    const int* erow = (const int*)d_in[1];
    const int* ecol = (const int*)d_in[2];
    const float* ew = (const float*)d_in[3];
    const float* W1 = (const float*)d_in[4];
    const float* b1 = (const float*)d_in[5];
    const float* W2 = (const float*)d_in[6];
    const float* b2 = (const float*)d_in[7];
    const float* W3 = (const float*)d_in[8];
    const float* b3 = (const float*)d_in[9];
    const float* W4 = (const float*)d_in[10];
    const float* b4 = (const float*)d_in[11];
    const float* W5 = (const float*)d_in[12];
    const float* b5 = (const float*)d_in[13];

    // Output layout: log_softmax(e5), e1, e2, e3, e4, e5
    float* out0 = (float*)d_out;
    float* e1 = out0 + (size_t)NN * NCLASS;
    float* e2 = e1 + (size_t)NN * NHID;
    float* e3 = e2 + (size_t)NN * NHID;
    float* e4 = e3 + (size_t)NN * NHID;
    float* e5 = e4 + (size_t)NN * NHID;

    // Workspace layout
    char* ws = (char*)d_ws;
    unsigned short* tmpb = (unsigned short*)ws; ws += (size_t)NN * NHID * 2;       // 6.4 MB
    float* tmp32 = (float*)ws; ws += (size_t)NN * NCLASS * sizeof(float);          // 3.2 MB
    float* h = (float*)ws;     ws += (size_t)NN * NHID * sizeof(float);            // 12.8 MB
    int* deg = (int*)ws;       ws += ((size_t)NN * 4 + 255) / 256 * 256;
    int* row_ptr = (int*)ws;   ws += ((size_t)(NN + 1) * 4 + 255) / 256 * 256;
    int* cursor = (int*)ws;    ws += ((size_t)NN * 4 + 255) / 256 * 256;
    int* blocksum = (int*)ws;  ws += ((size_t)NB_SCAN * 4 + 255) / 256 * 256;
    Edge* pairs = (Edge*)ws;   ws += (size_t)NE * sizeof(Edge);                    // 6.4 MB

    const int GB = (NN + 63) / 64;  // 782

    // ---- CSR build ----
    hipMemsetAsync(deg, 0, (size_t)NN * sizeof(int), stream);
    hist_kernel<<<(NE + 255) / 256, 256, 0, stream>>>(erow, deg, NE);
    scan_sum_kernel<<<NB_SCAN, 256, 0, stream>>>(deg, blocksum, NN);
    scan_top_kernel<<<1, 256, 0, stream>>>(blocksum, NB_SCAN);
    scan_final_kernel<<<NB_SCAN, 256, 0, stream>>>(deg, blocksum, row_ptr, cursor, NN);
    scatter_part_kernel<<<8 * SCHUNKS, 256, 0, stream>>>(erow, ecol, ew, cursor, pairs, NE);

    // ---- Layer 1 ----
    gemm64_kernel<NFEAT, true><<<GB, 256, 0, stream>>>(x, W1, tmpb, NN);
    spmm64b_kernel<true><<<NN / 4, 256, 0, stream>>>(tmpb, row_ptr, pairs, b1, e1, h, NN);

    // ---- Layer 2 ----
    gemm64_kernel<NHID, true><<<GB, 256, 0, stream>>>(h, W2, tmpb, NN);
    spmm64b_kernel<true><<<NN / 4, 256, 0, stream>>>(tmpb, row_ptr, pairs, b2, e2, h, NN);

    // ---- Layer 3 ----
    gemm64_kernel<NHID, true><<<GB, 256, 0, stream>>>(h, W3, tmpb, NN);
    spmm64b_kernel<true><<<NN / 4, 256, 0, stream>>>(tmpb, row_ptr, pairs, b3, e3, h, NN);

    // ---- Layer 4 ----
    gemm64_kernel<NHID, true><<<GB, 256, 0, stream>>>(h, W4, tmpb, NN);
    spmm64b_kernel<true><<<NN / 4, 256, 0, stream>>>(tmpb, row_ptr, pairs, b4, e4, h, NN);

    // ---- Layer 5: GEMM (fp32) -> SpMM fused with log_softmax ----
    gemm_kernel<NHID, NCLASS, 4><<<GB, 256, 0, stream>>>(h, W5, tmp32, NN);
    spmm16_lsm_kernel<<<(NN + 15) / 16, 256, 0, stream>>>(tmp32, row_ptr, pairs, b5, e5, out0, NN);
}